// Round 6
// baseline (273.487 us; speedup 1.0000x reference)
//
#include <hip/hip_runtime.h>
#include <hip/hip_bf16.h>
#include <stdint.h>

#define M_TOT 16384
#define K_TOT 4096
#define N_COLS 4096
#define NS 409
#define NP 448            // padded N: 4 col-quarters x 7 frags x 16
#define BM 64
#define BK 64
#define NT (K_TOT / BK)   // 64

#define BS_BYTES (NP * BK * 2)        // 57344 per buffer
#define LDS_TOTAL (2 * BS_BYTES)      // 114688

typedef __attribute__((ext_vector_type(4))) float f32x4;
typedef __attribute__((ext_vector_type(8))) short bf16x8;
typedef __attribute__((ext_vector_type(8))) unsigned short u16x8;

#define VMWAIT(N) asm volatile("s_waitcnt vmcnt(" #N ")" ::: "memory")
#define FULLWAIT() asm volatile("s_waitcnt vmcnt(0) lgkmcnt(0)" ::: "memory")
#define BAR() do { __builtin_amdgcn_s_barrier(); asm volatile("" ::: "memory"); } while (0)

__device__ inline unsigned short f2bf(float f) {
  unsigned u = __float_as_uint(f);
  u += 0x7FFFu + ((u >> 16) & 1u);  // RNE
  return (unsigned short)(u >> 16);
}

__device__ inline bf16x8 pack_bf8(f32x4 lo, f32x4 hi) {
  bf16x8 r;
  r[0] = (short)f2bf(lo[0]); r[1] = (short)f2bf(lo[1]);
  r[2] = (short)f2bf(lo[2]); r[3] = (short)f2bf(lo[3]);
  r[4] = (short)f2bf(hi[0]); r[5] = (short)f2bf(hi[1]);
  r[6] = (short)f2bf(hi[2]); r[7] = (short)f2bf(hi[3]);
  return r;
}

__device__ inline void gload_lds16(const void* g, void* l) {
  __builtin_amdgcn_global_load_lds(
      (const __attribute__((address_space(1))) void*)g,
      (__attribute__((address_space(3))) void*)l, 16, 0, 0);
}

// W fp32 [409][4096] -> bf16 [448][4096] in ws, zero rows 409..447
__global__ __launch_bounds__(256) void convert_w(const float* __restrict__ Wf,
                                                 unsigned short* __restrict__ Wb) {
  const int gt = blockIdx.x * 256 + threadIdx.x;
  const int row = gt >> 9;
  const int c8 = (gt & 511) << 3;
  u16x8 o;
  if (row < NS) {
    const f32x4 lo = *(const f32x4*)(Wf + (size_t)row * K_TOT + c8);
    const f32x4 hi = *(const f32x4*)(Wf + (size_t)row * K_TOT + c8 + 4);
    o = (u16x8)pack_bf8(lo, hi);
  } else {
#pragma unroll
    for (int i = 0; i < 8; ++i) o[i] = 0;
  }
  *(u16x8*)(Wb + (size_t)row * K_TOT + c8) = o;
}

// 256 blocks x 1024 threads (16 waves = 4/SIMD). Wave tile 16x112 (mrep=1,nrep=7).
// B: LDS dbuf via global_load_lds (waves 0..13 stage 4 chunks each, counted vmcnt).
// A: direct global fp32 -> in-reg bf16 (no LDS, no reg->LDS pipeline).
template <bool PRECONV>
__global__ __launch_bounds__(1024, 1) void gemm_fused(
    const float* __restrict__ X, const float* __restrict__ Wf,
    const unsigned short* __restrict__ Wb, const int* __restrict__ idx,
    float* __restrict__ OUT) {
  extern __shared__ char smem[];
  char* const B0 = smem;
  char* const B1 = smem + BS_BYTES;

  const int tid = threadIdx.x;
  const int lane = tid & 63;
  const int wv = tid >> 6;    // 0..15
  const int wq = wv >> 2;     // row group: rows wq*16 .. +15
  const int wn = wv & 3;      // column quarter: cols wn*112 .. +111
  const int l16 = lane & 15;
  const int kg = lane >> 4;   // 0..3
  const int row0 = blockIdx.x * BM;
  const size_t arow = (size_t)(row0 + wq * 16 + l16);

  int cidx[7];
#pragma unroll
  for (int j = 0; j < 7; ++j) {
    const int n = wn * 112 + j * 16 + l16;
    cidx[j] = (n < NS) ? idx[n] : -1;
  }

  f32x4 acc[7] = {};

  // ---- B staging: 56 x 1KB chunks (8 rows of 128B); waves 0..13 stage 4 each.
  // LDS linear dest; source pre-swizzled: content(phys p) = logical (p ^ (row&7)).
  auto stageB = [&](int t, char* Bb) {
    if (PRECONV) {
      if (wv < 14) {
#pragma unroll
        for (int c = 0; c < 4; ++c) {
          const int q = wv * 4 + c;         // chunk: rows q*8 .. q*8+7
          const int rowp = lane >> 3;       // row within chunk (0..7)
          const int p = lane & 7;           // physical 16B slot
          const int row = q * 8 + rowp;
          const int s = p ^ rowp;           // logical slot to fetch
          const unsigned short* src = Wb + (size_t)row * K_TOT + t * BK + s * 8;
          gload_lds16(src, Bb + q * 1024);
        }
      }
    } else {
      // fallback: W fp32 -> cvt -> swizzled ds_write (FULLWAIT sync path)
#pragma unroll
      for (int c = 0; c < 4; ++c) {
        const int id = c * 1024 + tid;      // 448 rows x 8 slots = 3584
        if (id < NP * 8) {
          const int row = id >> 3, sl = id & 7;
          f32x4 lo = {}, hi = {};
          if (row < NS) {
            const float* s = Wf + (size_t)row * K_TOT + t * BK + sl * 8;
            lo = *(const f32x4*)s;
            hi = *(const f32x4*)(s + 4);
          }
          *(bf16x8*)(Bb + row * 128 + ((sl ^ (row & 7)) << 4)) = pack_bf8(lo, hi);
        }
      }
    }
  };

  // ---- A: 4 x f32x4 direct from global (both ksteps of tile t) ----
  auto loadA = [&](int t, f32x4* rg) {
    const float* s = X + arow * K_TOT + t * BK + kg * 8;
    rg[0] = *(const f32x4*)(s + 0);
    rg[1] = *(const f32x4*)(s + 4);
    rg[2] = *(const f32x4*)(s + 32);
    rg[3] = *(const f32x4*)(s + 36);
  };

  auto compute = [&](const char* Bb, const f32x4* rg) {
#pragma unroll
    for (int ks = 0; ks < 2; ++ks) {
      const bf16x8 af = pack_bf8(rg[ks * 2], rg[ks * 2 + 1]);
#pragma unroll
      for (int j = 0; j < 7; ++j) {
        const int n = wn * 112 + j * 16 + l16;
        const bf16x8 b = *(const bf16x8*)(
            Bb + n * 128 + ((((ks << 2) | kg) ^ (n & 7)) << 4));
        acc[j] = __builtin_amdgcn_mfma_f32_16x16x32_bf16(af, b, acc[j], 0, 0, 0);
      }
    }
  };

  // ---- main loop ----
  // Queue per iter (PRECONV, staging waves): B(t)[4] | A(t)[4] | B(t+1)[4].
  // VMWAIT(8) drains exactly B(t); compiler's A-wait (vmcnt<=4) leaves B(t+1)
  // in flight across both barriers. Waves 14/15 stage nothing, skip the wait.
  stageB(0, B0);
#pragma unroll 1
  for (int t = 0; t < NT; ++t) {
    f32x4 rg[4];
    loadA(t, rg);
    stageB((t + 1) & (NT - 1), (t & 1) ? B0 : B1);
    if (PRECONV) {
      if (wv < 14) { VMWAIT(8); }
    } else {
      FULLWAIT();
    }
    BAR();
    compute((t & 1) ? B1 : B0, rg);
    BAR();
  }
  FULLWAIT();  // drain the final dummy stage before smem reuse
  BAR();

  // ---- fused epilogue: compose 4 full 4096-col rows per pass in LDS ----
  float* rowbuf = (float*)smem;  // 4 x 4096 f32 = 64 KB (< 112 KB allocated)
#pragma unroll 1
  for (int rb = 0; rb < 16; ++rb) {
#pragma unroll
    for (int z = 0; z < 4; ++z) {
      f32x4 zv = {};
      *(f32x4*)(rowbuf + z * N_COLS + tid * 4) = zv;
    }
    __syncthreads();
    // thread rows: r = wq*16 + kg*4 + q ; pass rb covers [4rb,4rb+4) <=> 4*wq+kg==rb
    if (4 * wq + kg == rb) {
#pragma unroll
      for (int q = 0; q < 4; ++q) {
        float* dst = rowbuf + q * N_COLS;
#pragma unroll
        for (int j = 0; j < 7; ++j)
          if (cidx[j] >= 0) dst[cidx[j]] = acc[j][q];
      }
    }
    __syncthreads();
    float* ob = OUT + (size_t)(row0 + rb * 4) * N_COLS;
#pragma unroll
    for (int z = 0; z < 4; ++z) {
      const int off = z * N_COLS + tid * 4;
      *(f32x4*)(ob + off) = *(const f32x4*)(rowbuf + off);
    }
    __syncthreads();
  }
}

extern "C" void kernel_launch(void* const* d_in, const int* in_sizes, int n_in,
                              void* d_out, int out_size, void* d_ws, size_t ws_size,
                              hipStream_t stream) {
  const float* x = (const float*)d_in[0];
  const float* w = (const float*)d_in[2];
  const int* idx = (const int*)d_in[3];
  float* out = (float*)d_out;

  const size_t need = (size_t)NP * K_TOT * 2;  // 3.67 MB bf16 W
  if (ws_size >= need) {
    unsigned short* wb = (unsigned short*)d_ws;
    convert_w<<<NP * K_TOT / 8 / 256, 256, 0, stream>>>(w, wb);
    hipFuncSetAttribute(reinterpret_cast<const void*>(&gemm_fused<true>),
                        hipFuncAttributeMaxDynamicSharedMemorySize, LDS_TOTAL);
    gemm_fused<true><<<M_TOT / BM, 1024, LDS_TOTAL, stream>>>(x, w, wb, idx, out);
  } else {
    hipFuncSetAttribute(reinterpret_cast<const void*>(&gemm_fused<false>),
                        hipFuncAttributeMaxDynamicSharedMemorySize, LDS_TOTAL);
    gemm_fused<false><<<M_TOT / BM, 1024, LDS_TOTAL, stream>>>(x, w, nullptr, idx, out);
  }
}